// Round 2
// baseline (691.807 us; speedup 1.0000x reference)
//
#include <hip/hip_runtime.h>

// Dequant: groups of 32 4-bit values packed as 17 int32 words/group
// (16 data words, low byte = two nibbles; word 16 = biased log2 scale).
//
// The 68 B group period breaks direct vectorized loads (odd-g bases are only
// 4 B aligned -> compiler can't emit dwordx2/x4 on the read side). So:
// stage 128 groups/block into LDS with coalesced int4 loads (16 B/lane),
// then dequantize out of LDS with coalesced float4 stores.

constexpr int kPGS = 17;                                  // words per packed group
constexpr int kGroupsPerBlock = 128;
constexpr int kWordsPerBlock = kGroupsPerBlock * kPGS;    // 2176 words = 8704 B (16B-divisible)
constexpr int kVec4PerBlock  = kGroupsPerBlock * 8;       // 1024 float4 outputs

__global__ __launch_bounds__(256) void dequant_mxfp4_kernel(
    const int* __restrict__ packed,
    const int* __restrict__ ebits_p,
    const int* __restrict__ mbits_p,
    float* __restrict__ out,
    int num_groups)
{
    __shared__ int lds[kWordsPerBlock];

    const int block_g0 = blockIdx.x * kGroupsPerBlock;
    const int groups_here = min(kGroupsPerBlock, num_groups - block_g0);
    const int words = groups_here * kPGS;
    const int* src = packed + (size_t)block_g0 * kPGS;

    if (words == kWordsPerBlock) {
        // Full block: 544 int4 loads, perfectly coalesced global_load_dwordx4.
        const int4* __restrict__ src4 = (const int4*)src;
        int4* lds4 = (int4*)lds;
        #pragma unroll
        for (int i = threadIdx.x; i < kWordsPerBlock / 4; i += 256)
            lds4[i] = src4[i];
    } else {
        for (int i = threadIdx.x; i < words; i += 256)
            lds[i] = src[i];
    }
    __syncthreads();

    // Uniform params (cached scalar-ish loads; negligible in a BW-bound kernel).
    const int ebits = ebits_p[0];
    const int mbits = mbits_p[0];
    const float clamp_max = (float)(1 << ((1 << ebits) - 1));                  // 8
    const float inv_max   = 1.0f / (clamp_max * (2.0f - exp2f((float)(-mbits)))); // 1/12

    float4* __restrict__ dst = (float4*)out + (size_t)blockIdx.x * kVec4PerBlock;
    const int nv = groups_here * 8;

    #pragma unroll
    for (int it = 0; it < 4; ++it) {
        int v = it * 256 + (int)threadIdx.x;   // float4 index within block
        if (v >= nv) break;
        int g = v >> 3;                        // local group
        int j = (v & 7) * 2;                   // first data word in group
        int w0 = lds[g * kPGS + j];
        int w1 = lds[g * kPGS + j + 1];
        int s  = lds[g * kPGS + 16];           // broadcast across 8 lanes

        int e = min(max(s - 127, -126), 127);
        float coef = ldexpf(inv_max, e);       // 2^e / max_val (exact pow2 scale)

        float4 r;
        r.x = ((float)(w0 & 15)        - clamp_max) * coef;
        r.y = ((float)((w0 >> 4) & 15) - clamp_max) * coef;
        r.z = ((float)(w1 & 15)        - clamp_max) * coef;
        r.w = ((float)((w1 >> 4) & 15) - clamp_max) * coef;
        dst[v] = r;                            // coalesced global_store_dwordx4
    }
}

extern "C" void kernel_launch(void* const* d_in, const int* in_sizes, int n_in,
                              void* d_out, int out_size, void* d_ws, size_t ws_size,
                              hipStream_t stream) {
    const int* packed  = (const int*)d_in[0];
    // d_in[1] = group_size (structural, =32; packing geometry hardcoded)
    const int* ebits_p = (const int*)d_in[2];
    const int* mbits_p = (const int*)d_in[3];
    float* out = (float*)d_out;

    int num_groups = in_sizes[0] / kPGS;                       // 4,194,304
    int grid = (num_groups + kGroupsPerBlock - 1) / kGroupsPerBlock;  // 32,768
    dequant_mxfp4_kernel<<<grid, 256, 0, stream>>>(packed, ebits_p, mbits_p, out, num_groups);
}